// Round 13
// baseline (14.987 us; speedup 1.0000x reference)
//
#include <hip/hip_runtime.h>

// CantileverPINN: loss = mean((d4/dx4 w(x) - 1)^2), w = MLP 1->15->30->60->1 tanh.
// Moment formulation (absmax 0.0 in R11/R12): f = deg-31 Chebyshev interpolant
// of w_xxxx, g = f - 1; loss = sum_{j,k} g_j g_k * 0.5*(S~_{j+k} + S~_{|j-k|}),
// S~_m = (1/N) sum_i T_m(t_i).
// SINGLE kernel, 64 blocks: 56 moment blocks + 8 node blocks.
//  - data handoff: distinct-address atomicExch (coherent, contention-free) +
//    materialized return (vmcnt drain) BEFORE the done-counter add (R7 pattern)
//  - tail selection: (atomicAdd(counter,1) & 63) == 63 -- fires exactly once
//    per call for ANY initial counter value (64 consecutive ints cover every
//    residue mod 64 once; 64 | 2^32). No zeroing, poison-proof, deterministic.
//  - tail reads via RELAXED agent-scope atomic loads (no ACQ_REL fence; R5
//    showed release/acquire cache maintenance costs ~27us).

#define MC 32          // Chebyshev coeffs / nodes
#define NM 63          // moments 0..62
#define MOMB 56        // moment blocks
#define NBLK 64        // total blocks (power of two!)

__device__ __forceinline__ float cos_turns(float phi) {   // cos(2*pi*phi)
    float r;
    asm("v_cos_f32 %0, %1" : "=v"(r) : "v"(phi));
    return r;
}

__device__ __forceinline__ float fast_tanh(float u) {
    float e = __expf(2.0f * u);
    return 1.0f - 2.0f / (e + 1.0f);   // e=inf -> 1, e=0 -> -1
}

struct TanhD { float t, s, p2, p3, p4; };

__device__ __forceinline__ TanhD tanh_derivs(float u0) {
    TanhD d;
    float t = fast_tanh(u0);
    float s = fmaf(-t, t, 1.0f);
    float ts = t * s;
    float t2 = t * t;
    d.t = t;
    d.s = s;
    d.p2 = -2.0f * ts;
    d.p3 = s * fmaf(4.0f, t2, -2.0f * s);          // s(4t^2 - 2s)
    d.p4 = 8.0f * ts * fmaf(-1.0f, t2, 2.0f * s);  // 8ts(2s - t^2)
    return d;
}

__device__ __forceinline__ void tanh_jet(const float u[5], float f[5]) {
    TanhD d = tanh_derivs(u[0]);
    float u1 = u[1], u2 = u[2], u3 = u[3], u4 = u[4];
    float u1sq = u1 * u1;
    f[0] = d.t;
    f[1] = d.s * u1;
    f[2] = fmaf(d.p2, u1sq, d.s * u2);
    f[3] = fmaf(d.p3, u1sq * u1, fmaf(3.0f * d.p2, u1 * u2, d.s * u3));
    f[4] = fmaf(d.p4, u1sq * u1sq,
           fmaf(6.0f * d.p3, u1sq * u2,
           fmaf(3.0f * d.p2, u2 * u2,
           fmaf(4.0f * d.p2, u1 * u3, d.s * u4))));
}

__device__ __forceinline__ float tanh_jet_d4(float u0, float u1, float u2,
                                             float u3, float u4) {
    TanhD d = tanh_derivs(u0);
    const float u1sq = u1 * u1;
    return fmaf(d.p4, u1sq * u1sq,
           fmaf(6.0f * d.p3, u1sq * u2,
           fmaf(3.0f * d.p2, u2 * u2,
           fmaf(4.0f * d.p2, u1 * u3, d.s * u4))));
}

// accumulate T_0..T_62 of one point into acc[]
__device__ __forceinline__ void accum_moments(float acc[NM], float xi) {
    const float tt = fmaf(2.0f, xi, -1.0f);
    const float t2 = tt + tt;
    float tp = 1.0f, tc = tt;
    acc[0] += 1.0f;
    acc[1] += tt;
    #pragma unroll
    for (int k = 2; k < NM; ++k) {
        const float tn = fmaf(t2, tc, -tp);
        acc[k] += tn;
        tp = tc; tc = tn;
    }
}

__global__ __launch_bounds__(256, 1)
void pinn_mono(const float* __restrict__ x,
               const float* __restrict__ W1, const float* __restrict__ b1,
               const float* __restrict__ W2, const float* __restrict__ b2,
               const float* __restrict__ W3, const float* __restrict__ b3,
               const float* __restrict__ W4,
               float* __restrict__ mom_partials,   // [NM][NBLK] k-major
               float* __restrict__ f_nodes,        // [MC]
               unsigned int* __restrict__ counter,
               float* __restrict__ out, int n, float inv_n) {
    __shared__ float smem[8512];
    __shared__ int sflag;

    const int t = threadIdx.x;
    const int lane = t & 63;
    const int wid = t >> 6;
    const int blk = blockIdx.x;

    if (blk < MOMB) {
        // ========== moment block: grid-stride float4, transpose-reduce ==========
        float acc[NM];
        #pragma unroll
        for (int k = 0; k < NM; ++k) acc[k] = 0.0f;

        const int nf4 = n >> 2;
        for (int i4 = blk * 256 + t; i4 < nf4; i4 += MOMB * 256) {
            const float4 v = ((const float4*)x)[i4];
            accum_moments(acc, v.x);
            accum_moments(acc, v.y);
            accum_moments(acc, v.z);
            accum_moments(acc, v.w);
        }
        if (blk == 0 && t == 0)
            for (int i = (nf4 << 2); i < n; ++i) accum_moments(acc, x[i]);

        // LDS-transpose reduction (R12), 2 chunks of <=32 moments
        float* trans = smem;                         // [32][257]
        float* red2  = smem + 32 * 257;              // [32][9]
        for (int c = 0; c < 2; ++c) {
            const int kbase = c * 32;
            const int kcnt = (c == 0) ? 32 : (NM - 32);
            __syncthreads();
            #pragma unroll
            for (int k = 0; k < 32; ++k)
                if (k < kcnt) trans[k * 257 + t] = acc[kbase + k];
            __syncthreads();
            {
                const int kl = t & 31, seg = t >> 5;
                if (kl < kcnt) {
                    const float* row = &trans[kl * 257 + seg * 32];
                    float s = 0.0f;
                    #pragma unroll
                    for (int u = 0; u < 32; ++u) s += row[u];
                    red2[kl * 9 + seg] = s;
                }
            }
            __syncthreads();
            if (t < kcnt) {
                float s = 0.0f;
                #pragma unroll
                for (int u = 0; u < 8; ++u) s += red2[t * 9 + u];
                // distinct-address coherent write; materialize -> vmcnt drain
                float old = atomicExch(&mom_partials[(kbase + t) * NBLK + blk], s);
                asm volatile("" :: "v"(old));
            }
        }
    } else {
        // ========== node block: 4 nodes, wave-per-node (R12) ==========
        float* sW1 = smem;          float* sB1 = smem + 15;
        float* sB2 = smem + 30;     float* sB3 = smem + 60;
        float* sW4 = smem + 120;
        float* sW2 = smem + 180;    // [15][30]
        float* sW3 = smem + 630;    // [30][60]
        float* gj  = smem + 2430;   // [4][15][5] wave-private
        float* h2  = smem + 2730;   // [4][30][5] wave-private

        for (int idx = t; idx < 450; idx += 256) sW2[idx] = W2[idx];
        for (int idx = t; idx < 1800; idx += 256) sW3[idx] = W3[idx];
        if (t < 15) { sW1[t] = W1[t]; sB1[t] = b1[t]; }
        if (t < 30) sB2[t] = b2[t];
        if (t < 60) { sB3[t] = b3[t]; sW4[t] = W4[t]; }
        __syncthreads();

        const int node = (blk - MOMB) * 4 + wid;      // 0..31
        const float phi = (float)(2 * node + 1) * (1.0f / 128.0f);
        const float xi  = fmaf(0.5f, cos_turns(phi), 0.5f);

        if (lane < 15) {                              // L1 jets
            const float w = sW1[lane];
            TanhD d = tanh_derivs(fmaf(w, xi, sB1[lane]));
            const float w2 = w * w;
            gj[wid * 75 + lane * 5 + 0] = d.t;
            gj[wid * 75 + lane * 5 + 1] = d.s * w;
            gj[wid * 75 + lane * 5 + 2] = d.p2 * w2;
            gj[wid * 75 + lane * 5 + 3] = d.p3 * w2 * w;
            gj[wid * 75 + lane * 5 + 4] = d.p4 * w2 * w2;
        }
        if (lane < 30) {                              // h2 jets (wave-private)
            float z[5] = { sB2[lane], 0.0f, 0.0f, 0.0f, 0.0f };
            #pragma unroll
            for (int i = 0; i < 15; ++i) {
                const float wij = sW2[i * 30 + lane];
                #pragma unroll
                for (int k = 0; k < 5; ++k)
                    z[k] = fmaf(wij, gj[wid * 75 + i * 5 + k], z[k]);
            }
            float h[5];
            tanh_jet(z, h);
            #pragma unroll
            for (int k = 0; k < 5; ++k) h2[wid * 150 + lane * 5 + k] = h[k];
        }
        float v = 0.0f;                               // z3 jets, d4, dot W4
        if (lane < 60) {
            float z[5] = { sB3[lane], 0.0f, 0.0f, 0.0f, 0.0f };
            #pragma unroll
            for (int i = 0; i < 30; ++i) {
                const float wim = sW3[i * 60 + lane];
                #pragma unroll
                for (int k = 0; k < 5; ++k)
                    z[k] = fmaf(wim, h2[wid * 150 + i * 5 + k], z[k]);
            }
            v = sW4[lane] * tanh_jet_d4(z[0], z[1], z[2], z[3], z[4]);
        }
        #pragma unroll
        for (int off = 32; off > 0; off >>= 1) v += __shfl_down(v, off, 64);
        if (lane == 0) {
            float old = atomicExch(&f_nodes[node], v);
            asm volatile("" :: "v"(old));
        }
    }

    // ---- done-counter: all writes of this block are committed (materialized
    // atomics + barrier). Mod-64 window picks exactly one tail block/call. ----
    __syncthreads();
    if (t == 0) {
        const unsigned int c = atomicAdd(counter, 1u);
        sflag = ((c & (NBLK - 1)) == (NBLK - 1)) ? 1 : 0;
    }
    __syncthreads();
    if (!sflag) return;

    // ================= tail (exactly one block per call) =================
    float* red  = smem;            // [63][4]
    float* sS   = smem + 256;      // [63]
    float* sf   = smem + 320;      // [32]
    float* sg   = smem + 352;      // [32]
    float* wsum = smem + 384;      // [4]

    {
        const int k = t >> 2, q = t & 3;
        if (k < NM) {
            float s = 0.0f;
            #pragma unroll
            for (int u = 0; u < 14; ++u)
                s += __hip_atomic_load(&mom_partials[k * NBLK + q * 14 + u],
                                       __ATOMIC_RELAXED, __HIP_MEMORY_SCOPE_AGENT);
            red[k * 4 + q] = s;
        }
        if (t < MC)
            sf[t] = __hip_atomic_load(&f_nodes[t],
                                      __ATOMIC_RELAXED, __HIP_MEMORY_SCOPE_AGENT);
    }
    __syncthreads();
    if (t < NM)
        sS[t] = (red[t * 4] + red[t * 4 + 1] + red[t * 4 + 2] + red[t * 4 + 3])
                * inv_n;
    if (t < MC) {                  // DCT-II -> f coeffs; g = f - 1
        float s = 0.0f;
        #pragma unroll
        for (int j = 0; j < MC; ++j) {
            const int num = (t * (2 * j + 1)) & 127;   // cos(pi*t*(j+.5)/32)
            s = fmaf(sf[j], cos_turns((float)num * (1.0f / 128.0f)), s);
        }
        const float c = s * ((t == 0) ? (1.0f / 32.0f) : (2.0f / 32.0f));
        sg[t] = (t == 0) ? (c - 1.0f) : c;
    }
    __syncthreads();

    // 1024 (j,k) pairs, 4 per thread
    float val = 0.0f;
    #pragma unroll
    for (int q = 0; q < 4; ++q) {
        const int p = t + 256 * q;
        const int j = p >> 5, k = p & 31;
        const int d = (j > k) ? (j - k) : (k - j);
        val = fmaf(sg[j] * sg[k], 0.5f * (sS[j + k] + sS[d]), val);
    }
    #pragma unroll
    for (int off = 32; off > 0; off >>= 1) val += __shfl_down(val, off, 64);
    if ((t & 63) == 0) wsum[t >> 6] = val;
    __syncthreads();
    if (t == 0) out[0] = wsum[0] + wsum[1] + wsum[2] + wsum[3];
}

extern "C" void kernel_launch(void* const* d_in, const int* in_sizes, int n_in,
                              void* d_out, int out_size, void* d_ws, size_t ws_size,
                              hipStream_t stream) {
    const float* x  = (const float*)d_in[0];
    const float* W1 = (const float*)d_in[1];
    const float* b1 = (const float*)d_in[2];
    const float* W2 = (const float*)d_in[3];
    const float* b2 = (const float*)d_in[4];
    const float* W3 = (const float*)d_in[5];
    const float* b3 = (const float*)d_in[6];
    const float* W4 = (const float*)d_in[7];
    // d_in[8] = b4: constant offset; vanishes under d^4/dx^4.

    const int n = in_sizes[0];

    float* ws           = (float*)d_ws;
    float* mom_partials = ws;                        // NM*NBLK = 4032 floats
    float* f_nodes      = ws + NM * NBLK;            // 32 floats
    unsigned int* counter = (unsigned int*)(ws + 4096);  // own cacheline

    pinn_mono<<<NBLK, 256, 0, stream>>>(x, W1, b1, W2, b2, W3, b3, W4,
                                        mom_partials, f_nodes, counter,
                                        (float*)d_out, n, 1.0f / (float)n);
}